// Round 19
// baseline (55.201 us; speedup 1.0000x reference)
//
#include <hip/hip_runtime.h>

// CCAMDec: out = x + scale * softmax(max_k(E)-E) @ y,  E = x·yᵀ over HW
// N=8, C=512, K=64, HW=4096. softmax(max-E) == softmax(-E) (shift invariance).
#define N_ 8
#define C_ 512
#define K_ 64
#define HW_ 4096
#define NQT 4                   // s-quarters in k_esm

typedef __attribute__((ext_vector_type(8))) short short8;   // 8 bf16 (4 VGPRs) MFMA A/B frag
typedef __attribute__((ext_vector_type(4))) float floatx4;  // MFMA C/D frag

// 8 f32 -> 8 bf16 via hardware v_cvt_pk_bf16_f32 (RNE, 1 instr / 2 elems)
__device__ __forceinline__ short8 cvt8(const float* __restrict__ p){
  float4 u = *(const float4*)p;
  float4 w = *(const float4*)(p + 4);
  union { unsigned u32[4]; short8 s; } r;
  asm("v_cvt_pk_bf16_f32 %0, %1, %2" : "=v"(r.u32[0]) : "v"(u.x), "v"(u.y));
  asm("v_cvt_pk_bf16_f32 %0, %1, %2" : "=v"(r.u32[1]) : "v"(u.z), "v"(u.w));
  asm("v_cvt_pk_bf16_f32 %0, %1, %2" : "=v"(r.u32[2]) : "v"(w.x), "v"(w.y));
  asm("v_cvt_pk_bf16_f32 %0, %1, %2" : "=v"(r.u32[3]) : "v"(w.z), "v"(w.w));
  return r.s;
}

// async global -> LDS, 16 B/lane (1 KB/wave), zero VGPR cost
__device__ __forceinline__ void gload16(const void* g, void* l){
  __builtin_amdgcn_global_load_lds(
      (const __attribute__((address_space(1))) void*)g,
      (__attribute__((address_space(3))) void*)l, 16, 0, 0);
}

// K0: y (f32, [n][k][s]) -> ybf (bf16 row-major [n][k][s]) and ytr (bf16 [n][s][k]).
// ytr store: per instruction 8 fully-contiguous 128 B rows (was 16 B scatter).
__global__ __launch_bounds__(256) void k_prep(const float* __restrict__ y,
                                              unsigned short* __restrict__ ybf,
                                              unsigned short* __restrict__ ytr){
  __shared__ unsigned short tile[64][72];
  int n  = blockIdx.x >> 6;                 // 64 s-tiles per batch
  int s0 = (blockIdx.x & 63) << 6;
  int tid = threadIdx.x;
  int k  = tid >> 2;
  int sc = (tid & 3) << 4;
  const float* yp = y + ((size_t)n * K_ + k) * HW_ + s0 + sc;
  union { unsigned short u16[16]; short8 s8[2]; uint4 q[2]; } u;
  u.s8[0] = cvt8(yp);
  u.s8[1] = cvt8(yp + 8);
  unsigned short* rp = ybf + ((size_t)n * K_ + k) * HW_ + s0 + sc;
  *(uint4*)rp       = u.q[0];
  *(uint4*)(rp + 8) = u.q[1];
#pragma unroll
  for (int j = 0; j < 16; ++j) tile[sc + j][k] = u.u16[j];
  __syncthreads();
  int s2 = tid >> 3;                        // 0..31
  int cb = (tid & 7) << 3;                  // col element (8 elems = 16 B)
  unsigned short* t0p = ytr + ((size_t)n * HW_ + s0 + s2) * K_ + cb;
  *(uint4*)t0p = *(const uint4*)&tile[s2][cb];
  unsigned short* t1p = ytr + ((size_t)n * HW_ + s0 + 32 + s2) * K_ + cb;
  *(uint4*)t1p = *(const uint4*)&tile[32 + s2][cb];
}

// K1: quarter-range energy, barrier-free wave-private engine at 3 blocks/CU.
// Grid 1024 = (n, 16c, s-quarter=1024).  512 thr (8 waves) -> 24 waves/CU.
// Wave (h=w>>2, q=w&3): s-slice [h*32,+32) of each 64-s chunk, k-quad q.
// Per chunk: 2 A-gloads (16 c-rows x 32 s, x dup 4x -> L2) + 1 B-gload,
// private 3KB double-buffer, granule-XOR pre-swizzle, vmcnt(3), ZERO
// barriers in the chunk loop (16 chunks).  Epilogue: LDS h-reduce ->
// one float4 store/thread into partial[qt] (plain stores, no sync).
__global__ __launch_bounds__(512) void k_esm(const float* __restrict__ x,
                                             const unsigned short* __restrict__ ybf,
                                             float* __restrict__ partial){
  __shared__ char smem[49152];      // 8 waves x 6 KB private staging
  const int bid = ((blockIdx.x & 7) << 7) | (blockIdx.x >> 3);  // XCD swizzle (1024%8==0)
  const int qt = bid & 3, ct = (bid >> 2) & 31, n = bid >> 7;
  const int tid = threadIdx.x;
  const int w = tid >> 6, l = tid & 63;
  const int lo = l & 15, hi = l >> 4;
  const int h = w >> 2, q = w & 3;          // h in {0,1}
  const int c0 = ct << 4;
  const int sb = qt << 10;                  // 1024 s per block

  // per-lane source addresses (chunk-invariant, granule-XOR pre-swizzled)
  const int ar = l >> 3;
  const int ag = (l & 7) ^ ar;              // true s-granule (4 f32)
  const char* asrc0 = (const char*)(x + ((size_t)n * C_ + c0 + 0 + ar) * HW_
                                    + sb + h * 32 + ag * 4);
  const char* asrc1 = (const char*)(x + ((size_t)n * C_ + c0 + 8 + ar) * HW_
                                    + sb + h * 32 + ag * 4);
  const int br = l >> 2;
  const int bg = (l & 3) ^ (br & 3);
  const char* bsrc = (const char*)(ybf + ((size_t)n * K_ + (q << 4) + br) * HW_
                                   + sb + h * 32 + bg * 8);

  char* wbase = smem + w * 6144;    // wave-private: [2 bufs][A 2K | B 1K]
  floatx4 acc = {0.f, 0.f, 0.f, 0.f};

#define ESTG(BUF, CH)                                                          \
  {                                                                            \
    gload16(asrc0 + (size_t)(CH) * 256, wbase + (BUF) * 3072);                 \
    gload16(asrc1 + (size_t)(CH) * 256, wbase + (BUF) * 3072 + 1024);          \
    gload16(bsrc  + (size_t)(CH) * 128, wbase + (BUF) * 3072 + 2048);          \
  }

#define ECMP(BUF)                                                              \
  {                                                                            \
    const char* Ab = wbase + (BUF) * 3072;                                     \
    float4 f0 = *(const float4*)(Ab + lo * 128 + (((hi << 1)       ^ (lo & 7)) << 4)); \
    float4 f1 = *(const float4*)(Ab + lo * 128 + ((((hi << 1) | 1) ^ (lo & 7)) << 4)); \
    union { unsigned u32[4]; short8 s; } xf;                                   \
    asm("v_cvt_pk_bf16_f32 %0, %1, %2" : "=v"(xf.u32[0]) : "v"(f0.x), "v"(f0.y)); \
    asm("v_cvt_pk_bf16_f32 %0, %1, %2" : "=v"(xf.u32[1]) : "v"(f0.z), "v"(f0.w)); \
    asm("v_cvt_pk_bf16_f32 %0, %1, %2" : "=v"(xf.u32[2]) : "v"(f1.x), "v"(f1.y)); \
    asm("v_cvt_pk_bf16_f32 %0, %1, %2" : "=v"(xf.u32[3]) : "v"(f1.z), "v"(f1.w)); \
    short8 yf = *(const short8*)(Ab + 2048 + lo * 64 + ((hi ^ (lo & 3)) << 4)); \
    /* swapped: A = y-frag (M=k), B = x-frag (N=c) -> D col=lo->c, row->k */   \
    acc = __builtin_amdgcn_mfma_f32_16x16x32_bf16(yf, xf.s, acc, 0, 0, 0);     \
  }

  ESTG(0, 0) ESTG(1, 1)            // 6 loads in flight

  for (int cp = 0; cp < 7; ++cp){
    int ch = cp << 1;
    asm volatile("s_waitcnt vmcnt(3)" ::: "memory");   // chunk ch ready
    ECMP(0)
    ESTG(0, ch + 2)
    asm volatile("s_waitcnt vmcnt(3)" ::: "memory");   // chunk ch+1 ready
    ECMP(1)
    ESTG(1, ch + 3)
  }
  asm volatile("s_waitcnt vmcnt(3)" ::: "memory");     // ch=14
  ECMP(0)
  asm volatile("s_waitcnt vmcnt(0)" ::: "memory");     // ch=15
  ECMP(1)
#undef ESTG
#undef ECMP

  // ---- epilogue: h-reduce via LDS (alias onto drained staging) ----
  __syncthreads();                  // all waves done reading staging
  float (*Els)[16][64] = (float (*)[16][64])smem;   // 8 KB alias
  *(floatx4*)&Els[h][lo][(q << 4) + (hi << 2)] = acc;
  __syncthreads();

  if (tid < 256){
    int c = tid >> 4, j = tid & 15;
    float4 t0 = *(const float4*)&Els[0][c][4 * j];
    float4 t1 = *(const float4*)&Els[1][c][4 * j];
    float4 e;
    e.x = t0.x + t1.x; e.y = t0.y + t1.y;
    e.z = t0.z + t1.z; e.w = t0.w + t1.w;
    *(float4*)(partial + (((size_t)(qt * N_ + n)) * C_ + c0 + c) * K_ + 4 * j) = e;
  }
}

// K2: out = x + scale * softmax(-E) @ y.  Grid 2048 (~8 blocks/CU), 256 thr.
// Prologue: PVLOAD(0) PREFETCHED, then reduce the 4 partial quarters (L2-hot),
// softmax(-E), att -> XOR-swizzled attl.  Main loop: swapped MFMA, A straight
// from ytr; T[16][68] transpose -> 256B-contiguous x-load / out-store.
__global__ __launch_bounds__(256) void k_pv(const float* __restrict__ x,
                                            const float* __restrict__ partial,
                                            const unsigned short* __restrict__ ytr,
                                            const float* __restrict__ scale,
                                            float* __restrict__ out){
  __shared__ float T[4][16][68];
  __shared__ char attl[2048];
  int bid = ((blockIdx.x & 7) << 8) | (blockIdx.x >> 3);  // XCD swizzle (2048%8==0)
  int sb = bid & 7;
  int ct = (bid >> 3) & 31;
  int n  = bid >> 8;
  int tid = threadIdx.x;
  int w  = tid >> 6;
  int l  = tid & 63, lo = l & 15, hi = l >> 4;
  int c0 = ct << 4;
  int sP = (sb << 9) + (w << 7);     // 512 per block, 128 per wave
  float sc = scale[0];

  const unsigned short* ybn = ytr + (size_t)n * HW_ * K_;
  float (*Tw)[68] = T[w];
  size_t xb[4];
#pragma unroll
  for (int rg = 0; rg < 4; ++rg)
    xb[rg] = ((size_t)n * C_ + c0 + (rg << 2) + hi) * HW_ + sP + (lo << 2);

  short8 aA[8]; float4 xA[4];
  short8 aB[8]; float4 xB[4];

#define PVLOAD(G, AV, XV)                                                      \
  {                                                                            \
    int sg = sP + (G) * 64;                                                    \
    _Pragma("unroll")                                                          \
    for (int t = 0; t < 4; ++t){                                               \
      const unsigned short* ap = ybn + (size_t)(sg + t * 16 + lo) * K_ + (hi << 3); \
      AV[2 * t]     = *(const short8*)(ap);                                    \
      AV[2 * t + 1] = *(const short8*)(ap + 32);                               \
    }                                                                          \
    _Pragma("unroll")                                                          \
    for (int rg = 0; rg < 4; ++rg)                                             \
      XV[rg] = *(const float4*)(x + xb[rg] + (G) * 64);                        \
  }

#define PVCOMP(G, AV, XV)                                                      \
  {                                                                            \
    _Pragma("unroll")                                                          \
    for (int t = 0; t < 4; ++t){                                               \
      floatx4 a2 = {0.f, 0.f, 0.f, 0.f};                                       \
      a2 = __builtin_amdgcn_mfma_f32_16x16x32_bf16(AV[2 * t],     batt0, a2, 0, 0, 0); \
      a2 = __builtin_amdgcn_mfma_f32_16x16x32_bf16(AV[2 * t + 1], batt1, a2, 0, 0, 0); \
      *(floatx4*)&Tw[lo][t * 16 + (hi << 2)] = a2;   /* D: col=lo->c, row->s */ \
    }                                                                          \
    _Pragma("unroll")                                                          \
    for (int rg = 0; rg < 4; ++rg){                                            \
      float4 v  = *(const float4*)&Tw[(rg << 2) + hi][lo << 2];                \
      float4 xv = XV[rg];                                                      \
      float4 o;                                                                \
      o.x = xv.x + sc * v.x; o.y = xv.y + sc * v.y;                            \
      o.z = xv.z + sc * v.z; o.w = xv.w + sc * v.w;                            \
      *(float4*)(out + xb[rg] + (G) * 64) = o;                                 \
    }                                                                          \
  }

  PVLOAD(0, aA, xA)                 // prefetch: latency hides under softmax

  // ---- softmax prologue: reduce 4 quarters ----
  {
    int c = tid >> 4, j = tid & 15;
    const float* pp = partial + ((size_t)n * C_ + c0 + c) * K_ + 4 * j;
    const size_t qs = (size_t)N_ * C_ * K_;
    float4 t0 = *(const float4*)(pp);
    float4 t1 = *(const float4*)(pp + qs);
    float4 t2 = *(const float4*)(pp + 2 * qs);
    float4 t3 = *(const float4*)(pp + 3 * qs);
    float e0 = t0.x + t1.x + t2.x + t3.x;
    float e1 = t0.y + t1.y + t2.y + t3.y;
    float e2 = t0.z + t1.z + t2.z + t3.z;
    float e3 = t0.w + t1.w + t2.w + t3.w;
    float m = fminf(fminf(e0, e1), fminf(e2, e3));
#pragma unroll
    for (int off = 8; off; off >>= 1) m = fminf(m, __shfl_xor(m, off, 16));
    float p0 = __expf(m - e0), p1 = __expf(m - e1);
    float p2 = __expf(m - e2), p3 = __expf(m - e3);
    float s = p0 + p1 + p2 + p3;
#pragma unroll
    for (int off = 8; off; off >>= 1) s += __shfl_xor(s, off, 16);
    float inv = 1.f / s;
    unsigned d0, d1;
    asm("v_cvt_pk_bf16_f32 %0, %1, %2" : "=v"(d0) : "v"(p0 * inv), "v"(p1 * inv));
    asm("v_cvt_pk_bf16_f32 %0, %1, %2" : "=v"(d1) : "v"(p2 * inv), "v"(p3 * inv));
    uint2 dd; dd.x = d0; dd.y = d1;
    *(uint2*)(attl + c * 128 + ((8 * j) ^ ((c & 7) << 4))) = dd;
  }
  __syncthreads();

  short8 batt0 = *(const short8*)(attl + lo * 128 + ((     hi * 16) ^ ((lo & 7) << 4)));
  short8 batt1 = *(const short8*)(attl + lo * 128 + ((64 + hi * 16) ^ ((lo & 7) << 4)));

  PVLOAD(1, aB, xB)
  PVCOMP(0, aA, xA)
  PVCOMP(1, aB, xB)
#undef PVLOAD
#undef PVCOMP
}

extern "C" void kernel_launch(void* const* d_in, const int* in_sizes, int n_in,
                              void* d_out, int out_size, void* d_ws, size_t ws_size,
                              hipStream_t stream){
  const float* x     = (const float*)d_in[0];
  const float* y     = (const float*)d_in[1];
  const float* scale = (const float*)d_in[2];
  float* out = (float*)d_out;

  // ws layout (12 MiB):
  //   partial : NQT * N*C*K f32 = 4 MiB @ 0    ([qt][n][c][k])
  //   ybf     : N*K*HW bf16     = 4 MiB @ 4 MiB
  //   ytr     : N*HW*K bf16     = 4 MiB @ 8 MiB
  char* ws = (char*)d_ws;
  float*          partial = (float*)(ws);
  unsigned short* ybf     = (unsigned short*)(ws + (4u<<20));
  unsigned short* ytr     = (unsigned short*)(ws + (8u<<20));

  k_prep <<<N_ * (HW_/64), 256, 0, stream>>>(y, ybf, ytr);
  k_esm  <<<N_ * 32 * NQT, 512, 0, stream>>>(x, ybf, partial);
  k_pv   <<<N_ * 32 * 8,   256, 0, stream>>>(x, partial, ytr, scale, out);
}

// Round 20
// 43.658 us; speedup vs baseline: 1.2644x; 1.2644x over previous
//
#include <hip/hip_runtime.h>

// CCAMDec: out = x + scale * softmax(max_k(E)-E) @ y,  E = x·yᵀ over HW
// N=8, C=512, K=64, HW=4096. softmax(max-E) == softmax(-E) (shift invariance).
#define N_ 8
#define C_ 512
#define K_ 64
#define HW_ 4096
#define NSP 4                   // s-splits in k_esm

typedef __attribute__((ext_vector_type(8))) short short8;   // 8 bf16 (4 VGPRs) MFMA A/B frag
typedef __attribute__((ext_vector_type(4))) float floatx4;  // MFMA C/D frag

// 8 f32 -> 8 bf16 via hardware v_cvt_pk_bf16_f32 (RNE, 1 instr / 2 elems)
__device__ __forceinline__ short8 cvt8(const float* __restrict__ p){
  float4 u = *(const float4*)p;
  float4 w = *(const float4*)(p + 4);
  union { unsigned u32[4]; short8 s; } r;
  asm("v_cvt_pk_bf16_f32 %0, %1, %2" : "=v"(r.u32[0]) : "v"(u.x), "v"(u.y));
  asm("v_cvt_pk_bf16_f32 %0, %1, %2" : "=v"(r.u32[1]) : "v"(u.z), "v"(u.w));
  asm("v_cvt_pk_bf16_f32 %0, %1, %2" : "=v"(r.u32[2]) : "v"(w.x), "v"(w.y));
  asm("v_cvt_pk_bf16_f32 %0, %1, %2" : "=v"(r.u32[3]) : "v"(w.z), "v"(w.w));
  return r.s;
}

// async global -> LDS, 16 B/lane (1 KB/wave), zero VGPR cost.
// LDS dest: wave-uniform base, HW scatters lane i at base + i*16.
__device__ __forceinline__ void gload16(const void* g, void* l){
  __builtin_amdgcn_global_load_lds(
      (const __attribute__((address_space(1))) void*)g,
      (__attribute__((address_space(3))) void*)l, 16, 0, 0);
}

// K0: y (f32, [n][k][s]) -> ybf2 (esm B-tiles, XOR baked) + ytr2 (PV A-frag order).
//   ybf2 : [n][q4][sc64][kk16][granule g (16B, stored at g^(kk&7))]  (4 MiB)
//   ytr2 : [n][st256][half2][lane64][8 elems]                        (4 MiB)
__global__ __launch_bounds__(256) void k_prep(const float* __restrict__ y,
                                              unsigned short* __restrict__ ybf2,
                                              unsigned short* __restrict__ ytr2){
  __shared__ unsigned short tile[64][72];
  int n  = blockIdx.x >> 6;                 // 64 s-tiles per batch
  int s0 = (blockIdx.x & 63) << 6;
  int tid = threadIdx.x;
  int k  = tid >> 2;
  int sc = (tid & 3) << 4;                  // 16 s per thread
  const float* yp = y + ((size_t)n * K_ + k) * HW_ + s0 + sc;
  union { unsigned short u16[16]; short8 s8[2]; uint4 q[2]; } u;
  u.s8[0] = cvt8(yp);
  u.s8[1] = cvt8(yp + 8);
  // ybf2 write (XOR-baked granules): q=k>>4, kk=k&15, sc64 = s0>>6
  {
    int q = k >> 4, kk = k & 15;
    size_t bbase = (((size_t)n * 4 + q) * 64 + (s0 >> 6)) * 1024 + kk * 64;
    int g0 = (tid & 3) << 1;                // granule (8 elems) index, 0..7
    *(uint4*)(ybf2 + bbase + (size_t)(((g0    ) ^ (kk & 7)) << 3)) = u.q[0];
    *(uint4*)(ybf2 + bbase + (size_t)(((g0 + 1) ^ (kk & 7)) << 3)) = u.q[1];
  }
#pragma unroll
  for (int j = 0; j < 16; ++j) tile[sc + j][k] = u.u16[j];
  __syncthreads();
  // ytr2 write: per 16-s tile, lane order (s=st*16+(l&15), k=(l>>4)*8+j)
  {
    int stl = tid >> 6, ll = tid & 63;
    int srow = stl * 16 + (ll & 15);
    int kcol = (ll >> 4) << 3;
    size_t tbase = ((size_t)n * 256 + (s0 >> 4) + stl) * 1024;
    *(uint4*)(ytr2 + tbase +       (ll << 3)) = *(const uint4*)&tile[srow][kcol];
    *(uint4*)(ytr2 + tbase + 512 + (ll << 3)) = *(const uint4*)&tile[srow][32 + kcol];
  }
}

// K1: partial energies, cooperative low-segment engine.  Grid 1024 =
// (n, 32 ct, 4 sp) -> 4 blocks/CU stagger.  256 thr / 4 waves; wave w owns
// k-quad w.  16 chunks of 64 s; per wave per chunk: 1 A-gload (4 x-rows x
// 256 B contiguous, source granule-XOR) + 2 B-gloads (FULLY contiguous 1 KB,
// XOR baked in ybf2).  2-buffer LDS (24 KB), counted vmcnt(3).  Waves own
// disjoint k -> no reduce; direct float4 partial stores.
__global__ __launch_bounds__(256) void k_esm(const float* __restrict__ x,
                                             const unsigned short* __restrict__ ybf2,
                                             float* __restrict__ partial){
  __shared__ char smem[24576];      // [2 bufs][Ax 4K | By 8K]
  const int bid = ((blockIdx.x & 7) << 7) | (blockIdx.x >> 3);  // XCD swizzle: n pinned/XCD
  const int sp = bid & 3, ct = (bid >> 2) & 31, n = bid >> 7;
  const int tid = threadIdx.x;
  const int w = tid >> 6, l = tid & 63;
  const int lo = l & 15, hi = l >> 4;
  const int c0 = ct << 4;
  const int sb = sp << 10;          // 1024 s per block

  // A-gload source: wave w stages x rows 4w..4w+3, 256 B each (chunk = 64 s).
  const int r = (w << 2) + (l >> 4);
  const char* asrc = (const char*)(x + ((size_t)n * C_ + c0 + r) * HW_ + sb)
                     + (((l & 15) ^ (r & 7)) << 4);
  // B-gload source: wave w's quad tile in ybf2 (contiguous 2 KB per chunk).
  const char* bsrc = (const char*)ybf2
                     + (((size_t)n * 4 + w) * 64 + (sb >> 6)) * 2048 + (l << 4);

  floatx4 acc = {0.f, 0.f, 0.f, 0.f};

#define STAGE(BUF, CH)                                                         \
  {                                                                            \
    gload16(asrc + (size_t)(CH) * 256,         smem + (BUF) * 12288 + (w << 10)); \
    gload16(bsrc + (size_t)(CH) * 2048,        smem + (BUF) * 12288 + 4096 + (w << 11)); \
    gload16(bsrc + (size_t)(CH) * 2048 + 1024, smem + (BUF) * 12288 + 4096 + (w << 11) + 1024); \
  }

#define ECMP(BUF)                                                              \
  {                                                                            \
    const char* Ax = smem + (BUF) * 12288;                                     \
    const char* By = smem + (BUF) * 12288 + 4096 + (w << 11);                  \
    _Pragma("unroll")                                                          \
    for (int ss = 0; ss < 2; ++ss){                                            \
      int g0 = (ss << 3) + (hi << 1);                                          \
      float4 f0 = *(const float4*)(Ax + lo * 256 + (((g0    ) ^ (lo & 7)) << 4)); \
      float4 f1 = *(const float4*)(Ax + lo * 256 + (((g0 + 1) ^ (lo & 7)) << 4)); \
      union { unsigned u32[4]; short8 s; } xf;                                 \
      asm("v_cvt_pk_bf16_f32 %0, %1, %2" : "=v"(xf.u32[0]) : "v"(f0.x), "v"(f0.y)); \
      asm("v_cvt_pk_bf16_f32 %0, %1, %2" : "=v"(xf.u32[1]) : "v"(f0.z), "v"(f0.w)); \
      asm("v_cvt_pk_bf16_f32 %0, %1, %2" : "=v"(xf.u32[2]) : "v"(f1.x), "v"(f1.y)); \
      asm("v_cvt_pk_bf16_f32 %0, %1, %2" : "=v"(xf.u32[3]) : "v"(f1.z), "v"(f1.w)); \
      short8 yf = *(const short8*)(By + lo * 128 + ((((ss << 2) + hi) ^ (lo & 7)) << 4)); \
      /* swapped: A = y-frag (M=k), B = x-frag (N=c) -> D col=lo->c, row->k */ \
      acc = __builtin_amdgcn_mfma_f32_16x16x32_bf16(yf, xf.s, acc, 0, 0, 0);   \
    }                                                                          \
  }

  STAGE(0, 0)

#pragma unroll
  for (int ch = 0; ch < 16; ++ch){
    const int cur = ch & 1;
    if (ch + 1 < 16){
      STAGE(cur ^ 1, ch + 1)
      asm volatile("s_waitcnt vmcnt(3)" ::: "memory");   // own chunk-ch loads done
    } else {
      asm volatile("s_waitcnt vmcnt(0)" ::: "memory");
    }
    __builtin_amdgcn_s_barrier();       // whole tile staged (each wave waited its own)
    __builtin_amdgcn_sched_barrier(0);
    ECMP(cur)
    __builtin_amdgcn_sched_barrier(0);
    __builtin_amdgcn_s_barrier();       // cur buffer free for overwrite
  }
#undef STAGE
#undef ECMP

  // D: col = lo -> c = c0+lo ; row = hi*4+r -> k = w*16 + hi*4 + r
  float* pp = partial + (((size_t)sp * N_ + n) * C_ + c0 + lo) * K_ + (w << 4) + (hi << 2);
  *(floatx4*)pp = acc;
}

// K2: out = x + scale * softmax(-E) @ y.  Grid 2048 (~8 blocks/CU), 256 thr.
// Prologue: PVLOAD(0) prefetched; reduce 4 partial slices (L2-hot); softmax;
// att -> XOR-swizzled attl.  Main loop: swapped MFMA; A-frags via ytr2 =
// ONE contiguous 1 KB load per instruction; T[16][68] transpose ->
// 256B-contiguous x-load / out-store.
__global__ __launch_bounds__(256) void k_pv(const float* __restrict__ x,
                                            const float* __restrict__ partial,
                                            const unsigned short* __restrict__ ytr2,
                                            const float* __restrict__ scale,
                                            float* __restrict__ out){
  __shared__ float T[4][16][68];
  __shared__ char attl[2048];
  int bid = ((blockIdx.x & 7) << 8) | (blockIdx.x >> 3);  // XCD swizzle: n pinned/XCD
  int sb = bid & 7;
  int ct = (bid >> 3) & 31;
  int n  = bid >> 8;
  int tid = threadIdx.x;
  int w  = tid >> 6;
  int l  = tid & 63, lo = l & 15, hi = l >> 4;
  int c0 = ct << 4;
  int sP = (sb << 9) + (w << 7);     // 512 per block, 128 per wave
  float sc = scale[0];

  const unsigned short* y2 = ytr2 + (size_t)n * 256 * 1024;
  const int st0 = sP >> 4;           // wave's first 16-s tile
  float (*Tw)[68] = T[w];
  size_t xb[4];
#pragma unroll
  for (int rg = 0; rg < 4; ++rg)
    xb[rg] = ((size_t)n * C_ + c0 + (rg << 2) + hi) * HW_ + sP + (lo << 2);

  short8 aA[8]; float4 xA[4];
  short8 aB[8]; float4 xB[4];

#define PVLOAD(G, AV, XV)                                                      \
  {                                                                            \
    _Pragma("unroll")                                                          \
    for (int t = 0; t < 4; ++t){                                               \
      const unsigned short* ap = y2 + (size_t)(st0 + (G) * 4 + t) * 1024 + (l << 3); \
      AV[2 * t]     = *(const short8*)(ap);                                    \
      AV[2 * t + 1] = *(const short8*)(ap + 512);                              \
    }                                                                          \
    _Pragma("unroll")                                                          \
    for (int rg = 0; rg < 4; ++rg)                                             \
      XV[rg] = *(const float4*)(x + xb[rg] + (G) * 64);                        \
  }

#define PVCOMP(G, AV, XV)                                                      \
  {                                                                            \
    _Pragma("unroll")                                                          \
    for (int t = 0; t < 4; ++t){                                               \
      floatx4 a2 = {0.f, 0.f, 0.f, 0.f};                                       \
      a2 = __builtin_amdgcn_mfma_f32_16x16x32_bf16(AV[2 * t],     batt0, a2, 0, 0, 0); \
      a2 = __builtin_amdgcn_mfma_f32_16x16x32_bf16(AV[2 * t + 1], batt1, a2, 0, 0, 0); \
      *(floatx4*)&Tw[lo][t * 16 + (hi << 2)] = a2;   /* D: col=lo->c, row->s */ \
    }                                                                          \
    _Pragma("unroll")                                                          \
    for (int rg = 0; rg < 4; ++rg){                                            \
      float4 v  = *(const float4*)&Tw[(rg << 2) + hi][lo << 2];                \
      float4 xv = XV[rg];                                                      \
      float4 o;                                                                \
      o.x = xv.x + sc * v.x; o.y = xv.y + sc * v.y;                            \
      o.z = xv.z + sc * v.z; o.w = xv.w + sc * v.w;                            \
      *(float4*)(out + xb[rg] + (G) * 64) = o;                                 \
    }                                                                          \
  }

  PVLOAD(0, aA, xA)                 // prefetch: latency hides under softmax

  // ---- softmax prologue: reduce 4 slices ----
  {
    int c = tid >> 4, j = tid & 15;
    const float* pp = partial + ((size_t)n * C_ + c0 + c) * K_ + 4 * j;
    const size_t qs = (size_t)N_ * C_ * K_;
    float4 t0 = *(const float4*)(pp);
    float4 t1 = *(const float4*)(pp + qs);
    float4 t2 = *(const float4*)(pp + 2 * qs);
    float4 t3 = *(const float4*)(pp + 3 * qs);
    float e0 = t0.x + t1.x + t2.x + t3.x;
    float e1 = t0.y + t1.y + t2.y + t3.y;
    float e2 = t0.z + t1.z + t2.z + t3.z;
    float e3 = t0.w + t1.w + t2.w + t3.w;
    float m = fminf(fminf(e0, e1), fminf(e2, e3));
#pragma unroll
    for (int off = 8; off; off >>= 1) m = fminf(m, __shfl_xor(m, off, 16));
    float p0 = __expf(m - e0), p1 = __expf(m - e1);
    float p2 = __expf(m - e2), p3 = __expf(m - e3);
    float s = p0 + p1 + p2 + p3;
#pragma unroll
    for (int off = 8; off; off >>= 1) s += __shfl_xor(s, off, 16);
    float inv = 1.f / s;
    unsigned d0, d1;
    asm("v_cvt_pk_bf16_f32 %0, %1, %2" : "=v"(d0) : "v"(p0 * inv), "v"(p1 * inv));
    asm("v_cvt_pk_bf16_f32 %0, %1, %2" : "=v"(d1) : "v"(p2 * inv), "v"(p3 * inv));
    uint2 dd; dd.x = d0; dd.y = d1;
    *(uint2*)(attl + c * 128 + ((8 * j) ^ ((c & 7) << 4))) = dd;
  }
  __syncthreads();

  short8 batt0 = *(const short8*)(attl + lo * 128 + ((     hi * 16) ^ ((lo & 7) << 4)));
  short8 batt1 = *(const short8*)(attl + lo * 128 + ((64 + hi * 16) ^ ((lo & 7) << 4)));

  PVLOAD(1, aB, xB)
  PVCOMP(0, aA, xA)
  PVCOMP(1, aB, xB)
#undef PVLOAD
#undef PVCOMP
}

extern "C" void kernel_launch(void* const* d_in, const int* in_sizes, int n_in,
                              void* d_out, int out_size, void* d_ws, size_t ws_size,
                              hipStream_t stream){
  const float* x     = (const float*)d_in[0];
  const float* y     = (const float*)d_in[1];
  const float* scale = (const float*)d_in[2];
  float* out = (float*)d_out;

  // ws layout (12 MiB):
  //   partial : NSP * N*C*K f32 = 4 MiB @ 0    ([sp][n][c][k])
  //   ybf2    : 4 MiB @ 4 MiB   (esm B-tiles, XOR baked)
  //   ytr2    : 4 MiB @ 8 MiB   (PV A-frag lane order)
  char* ws = (char*)d_ws;
  float*          partial = (float*)(ws);
  unsigned short* ybf2    = (unsigned short*)(ws + (4u<<20));
  unsigned short* ytr2    = (unsigned short*)(ws + (8u<<20));

  k_prep <<<N_ * (HW_/64), 256, 0, stream>>>(y, ybf2, ytr2);
  k_esm  <<<N_ * 32 * NSP, 256, 0, stream>>>(x, ybf2, partial);
  k_pv   <<<N_ * 32 * 8,   256, 0, stream>>>(x, partial, ytr2, scale, out);
}